// Round 6
// baseline (313.145 us; speedup 1.0000x reference)
//
#include <hip/hip_runtime.h>
#include <math.h>

// Problem dims (fixed)
#define NB 16
#define NV 12
#define NROWS 192          // NB*NV
#define DRAW 200704
#define KOUT 256
#define DFEAT 1024
#define NG 8
#define NCLS 40

// K1: 512 blocks = 256 K-chunks x 2 col-halves. KC=784 -> 25 steps of 32
// (step 24 half-masked: only k-octets g4<2 valid).
#define NCHUNK 256
#define KC 784

// workspace layout (bytes)
#define WS_SCORE 0                       // [192] f32
#define WS_DESC  1024                    // [16][1024] f32
#define WS_Z1    66560                   // [16][512] f32
#define WS_Z2    99328                   // [16][256] f32
#define WS_PART  131072                  // [256][192][256] f32

typedef __attribute__((ext_vector_type(8))) short short8;
typedef __attribute__((ext_vector_type(4))) float f32x4;

// split x -> hi(bf16 trunc) + lo(bf16 trunc of exact residual); pack 4 elems
__device__ __forceinline__ void cvt4(float4 v, uint2& hi, uint2& lo) {
    unsigned b0 = __float_as_uint(v.x), b1 = __float_as_uint(v.y);
    unsigned b2 = __float_as_uint(v.z), b3 = __float_as_uint(v.w);
    hi.x = (b0 >> 16) | (b1 & 0xffff0000u);
    hi.y = (b2 >> 16) | (b3 & 0xffff0000u);
    float r0 = v.x - __uint_as_float(b0 & 0xffff0000u);
    float r1 = v.y - __uint_as_float(b1 & 0xffff0000u);
    float r2 = v.z - __uint_as_float(b2 & 0xffff0000u);
    float r3 = v.w - __uint_as_float(b3 & 0xffff0000u);
    lo.x = (__float_as_uint(r0) >> 16) | (__float_as_uint(r1) & 0xffff0000u);
    lo.y = (__float_as_uint(r2) >> 16) | (__float_as_uint(r3) & 0xffff0000u);
}

__device__ __forceinline__ short8 mk8(uint2 a, uint2 b) {
    union { unsigned u[4]; short8 s; } x;
    x.u[0] = a.x; x.u[1] = a.y; x.u[2] = b.x; x.u[3] = b.y;
    return x.s;
}

// issue step-S global loads into named reg buffers (f32). GUARD=1 for step 24
// (only k-octets g4<2 valid). A: 2 dwordx4/tile; B: 8 dwords strided 1KB.
#define K1_LOAD(DA, DB, S, GUARD)                                              \
  {                                                                            \
    const int koff = (S) * 32;                                                 \
    const float4 f4z = make_float4(0.f, 0.f, 0.f, 0.f);                        \
    _Pragma("unroll") for (int tm = 0; tm < 3; ++tm) {                         \
      const float* ap = aP[tm] + koff;                                         \
      bool ok = aact[tm] && (!(GUARD) || g4 < 2);                              \
      DA[tm][0] = ok ? *(const float4*)(ap) : f4z;                             \
      DA[tm][1] = ok ? *(const float4*)(ap + 4) : f4z;                         \
    }                                                                          \
    _Pragma("unroll") for (int tn = 0; tn < 4; ++tn) {                         \
      const float* bp = bP[tn] + (size_t)koff * KOUT;                          \
      bool okb = !(GUARD) || g4 < 2;                                           \
      _Pragma("unroll") for (int q = 0; q < 8; ++q)                            \
        DB[tn][q] = okb ? bp[(size_t)q * KOUT] : 0.f;                          \
    }                                                                          \
  }

// cvt f32 regs -> bf16 hi/lo fragments + 36 MFMAs (bf16x3)
#define K1_MMA(AS, BS)                                                         \
  {                                                                            \
    short8 ah[3], al[3];                                                       \
    _Pragma("unroll") for (int tm = 0; tm < 3; ++tm) {                         \
      uint2 h0, l0, h1, l1;                                                    \
      cvt4(AS[tm][0], h0, l0); cvt4(AS[tm][1], h1, l1);                        \
      ah[tm] = mk8(h0, h1); al[tm] = mk8(l0, l1);                              \
    }                                                                          \
    _Pragma("unroll") for (int tn = 0; tn < 4; ++tn) {                         \
      uint2 h0, l0, h1, l1;                                                    \
      cvt4(make_float4(BS[tn][0], BS[tn][1], BS[tn][2], BS[tn][3]), h0, l0);   \
      cvt4(make_float4(BS[tn][4], BS[tn][5], BS[tn][6], BS[tn][7]), h1, l1);   \
      short8 bh = mk8(h0, h1), bl = mk8(l0, l1);                               \
      _Pragma("unroll") for (int tm = 0; tm < 3; ++tm) {                       \
        acc[tm][tn] = __builtin_amdgcn_mfma_f32_16x16x32_bf16(ah[tm], bh, acc[tm][tn], 0, 0, 0); \
        acc[tm][tn] = __builtin_amdgcn_mfma_f32_16x16x32_bf16(ah[tm], bl, acc[tm][tn], 0, 0, 0); \
        acc[tm][tn] = __builtin_amdgcn_mfma_f32_16x16x32_bf16(al[tm], bh, acc[tm][tn], 0, 0, 0); \
      }                                                                        \
    }                                                                          \
  }

// Barrier-free MFMA split-K/split-N GEMM. NO LDS: each lane loads its MFMA
// fragment elements directly from global (A rows are wave-private; B cols
// duplicated x4 across wm-waves -> L1 hits). Register double-buffer, loads
// one full step ahead; waves fully self-scheduled.
// Frag layout (verified R2-R5): lane l holds X[{row|col} = l&15][k = (l>>4)*8 + q].
// Co-XCD map: both col-halves of a chunk share bid%8 (same XCD L2 for A reuse).
__global__ __launch_bounds__(512, 2)
void k1_mfma(const float* __restrict__ raw, const float* __restrict__ W1,
             const int* __restrict__ vnum, float* __restrict__ part)
{
    const int t = threadIdx.x;
    const int g8 = blockIdx.x & 7;
    const int i8 = blockIdx.x >> 3;
    const int c = g8 * 32 + (i8 >> 1);
    const int colbase = (i8 & 1) * 128;
    const int d0 = c * KC;
    const int lane = t & 63;
    const int wave = t >> 6;
    const int wm = wave >> 1, wn = wave & 1;
    const int r15 = lane & 15, g4 = lane >> 4;

    // per-lane A row pointers + activity (inactive views -> zeros; their P
    // rows are garbage-tolerant: mask applies at binning)
    const float* aP[3];
    bool aact[3];
#pragma unroll
    for (int tm = 0; tm < 3; ++tm) {
        int row = wm * 48 + tm * 16 + r15;
        aact[tm] = (row % NV) < vnum[row / NV];
        aP[tm] = raw + (size_t)row * DRAW + d0 + g4 * 8;
    }
    // per-lane B col pointers
    const float* bP[4];
#pragma unroll
    for (int tn = 0; tn < 4; ++tn) {
        int col = colbase + wn * 64 + tn * 16 + r15;
        bP[tn] = W1 + (size_t)(d0 + g4 * 8) * KOUT + col;
    }

    f32x4 acc[3][4];
#pragma unroll
    for (int i = 0; i < 3; ++i)
#pragma unroll
        for (int j = 0; j < 4; ++j) acc[i][j] = (f32x4){0.f, 0.f, 0.f, 0.f};

    float4 Aa[3][2], Ab[3][2];
    float Ba[4][8], Bb[4][8];

    K1_LOAD(Aa, Ba, 0, 0);
#pragma unroll 1
    for (int sp = 0; sp < 11; ++sp) {
        K1_LOAD(Ab, Bb, 2 * sp + 1, 0);  K1_MMA(Aa, Ba);   // compute 2sp
        K1_LOAD(Aa, Ba, 2 * sp + 2, 0);  K1_MMA(Ab, Bb);   // compute 2sp+1
    }
    K1_LOAD(Ab, Bb, 23, 0);  K1_MMA(Aa, Ba);   // step 22
    K1_LOAD(Aa, Ba, 24, 1);  K1_MMA(Ab, Bb);   // step 23 (load 24 guarded)
    K1_MMA(Aa, Ba);                             // step 24

    // epilogue: C/D layout col=lane&15, row=(lane>>4)*4+r; non-atomic partials
    float* dst0 = part + (size_t)c * NROWS * KOUT;
#pragma unroll
    for (int tm = 0; tm < 3; ++tm) {
        int row0 = wm * 48 + tm * 16 + g4 * 4;
#pragma unroll
        for (int tn = 0; tn < 4; ++tn) {
            int col = colbase + wn * 64 + tn * 16 + r15;
            float* dst = dst0 + (size_t)row0 * KOUT + col;
            f32x4 a = acc[tm][tn];
#pragma unroll
            for (int r = 0; r < 4; ++r) dst[(size_t)r * KOUT] = a[r];
        }
    }
}

// fused 256-way partial reduce + score head. One block per row (192 x 1024).
// thread = (cg = t>>8 of 4 chunk-groups, col = t&255); each sums 64 chunks.
__global__ __launch_bounds__(1024)
void k2_score(const float* __restrict__ part, const float* __restrict__ b1,
              const float* __restrict__ W2, const float* __restrict__ b2,
              float* __restrict__ score)
{
    const int row = blockIdx.x, t = threadIdx.x;
    const int col = t & 255, cg = t >> 8;
    __shared__ float red[4][KOUT];
    __shared__ float r2[4];
    const float* p = part + (size_t)(cg * 64) * NROWS * KOUT + (size_t)row * KOUT + col;
    float s = 0.f;
#pragma unroll 8
    for (int i = 0; i < 64; ++i) s += p[(size_t)i * NROWS * KOUT];
    red[cg][col] = s;
    __syncthreads();
    if (t < 256) {
        float v = red[0][col] + red[1][col] + red[2][col] + red[3][col];
        float h = fmaxf(v + b1[col], 0.f) * W2[col];
        for (int o = 32; o > 0; o >>= 1) h += __shfl_down(h, o, 64);
        if ((t & 63) == 0) r2[t >> 6] = h;
    }
    __syncthreads();
    if (t == 0) {
        float sm = r2[0] + r2[1] + r2[2] + r2[3];
        float sraw = fmaxf(sm + b2[0], 0.f);
        score[row] = 1.f / (1.f + expf(-tanhf(fabsf(sraw))));
    }
}

// binning -> per-view coeff -> desc. One block per sample.
__global__ __launch_bounds__(512)
void k3_bindesc(const float* __restrict__ score, const int* __restrict__ vnum,
                const float* __restrict__ fv, float* __restrict__ desc)
{
    const int n = blockIdx.x, t = threadIdx.x;
    __shared__ float coeffL[NV], wsum[NG], wt[NG], wtotS;
    __shared__ int cnt[NG];
    if (t < NG) { cnt[t] = 0; wsum[t] = 0.f; }
    __syncthreads();
    const int vn = vnum[n];
    const bool act = (t < NV) && (t < vn);
    float sc = 0.f; int b = 0;
    if (act) {
        sc = score[n * NV + t];
        b = (int)floorf(sc * 8.f); b = b < 0 ? 0 : (b > 7 ? 7 : b);
        atomicAdd(&cnt[b], 1);
    }
    __syncthreads();
    if (act) atomicAdd(&wsum[b], ceilf(sc * (float)cnt[b]));  // integer-valued: order-exact
    __syncthreads();
    if (t < NG) wt[t] = (cnt[t] > 0) ? wsum[t] / (float)cnt[t] : 0.f;
    __syncthreads();
    if (t == 0) { float x = 0.f; for (int g = 0; g < NG; ++g) x += wt[g]; wtotS = x; }
    __syncthreads();
    if (t < NV) coeffL[t] = act ? wt[b] / ((float)cnt[b] * wtotS) : 0.f;
    __syncthreads();
#pragma unroll
    for (int p = 0; p < 2; ++p) {
        int d = t + p * 512;
        float a = 0.f;
#pragma unroll
        for (int v = 0; v < NV; ++v)
            a = fmaf(coeffL[v], fv[((size_t)n * NV + v) * DFEAT + d], a);
        desc[n * DFEAT + d] = a;
    }
}

// z1 = relu(desc @ Wf1 + bf1): j-sliced blocks, all 16 samples inside the
// block -> Wf1 read once overall. block 512 = 64 j x 8 sample-pairs.
__global__ __launch_bounds__(512)
void kz1(const float* __restrict__ desc, const float* __restrict__ Wf1,
         const float* __restrict__ bf1, float* __restrict__ z1)
{
    __shared__ float dL[NB * DFEAT];
    const int t = threadIdx.x;
#pragma unroll
    for (int i = 0; i < 8; ++i)
        *(float4*)&dL[(i * 512 + t) * 4] = *(const float4*)&desc[(i * 512 + t) * 4];
    __syncthreads();
    const int j = blockIdx.x * 64 + (t & 63);
    const int n0 = (t >> 6) * 2;
    float a0 = 0.f, a1 = 0.f, a2 = 0.f, a3 = 0.f;
#pragma unroll 4
    for (int d = 0; d < DFEAT; d += 2) {
        float w0 = Wf1[(size_t)d * 512 + j];
        float w1 = Wf1[(size_t)(d + 1) * 512 + j];
        a0 = fmaf(dL[n0 * DFEAT + d], w0, a0);
        a1 = fmaf(dL[(n0 + 1) * DFEAT + d], w0, a1);
        a2 = fmaf(dL[n0 * DFEAT + d + 1], w1, a2);
        a3 = fmaf(dL[(n0 + 1) * DFEAT + d + 1], w1, a3);
    }
    z1[n0 * 512 + j] = fmaxf(a0 + a2 + bf1[j], 0.f);
    z1[(n0 + 1) * 512 + j] = fmaxf(a1 + a3 + bf1[j], 0.f);
}

// z2 = relu(z1 @ Wf2 + bf2)
__global__ __launch_bounds__(512)
void kz2(const float* __restrict__ z1, const float* __restrict__ Wf2,
         const float* __restrict__ bf2, float* __restrict__ z2)
{
    __shared__ float zL[NB * 512];
    const int t = threadIdx.x;
#pragma unroll
    for (int i = 0; i < 4; ++i)
        *(float4*)&zL[(i * 512 + t) * 4] = *(const float4*)&z1[(i * 512 + t) * 4];
    __syncthreads();
    const int j = blockIdx.x * 64 + (t & 63);
    const int n0 = (t >> 6) * 2;
    float a0 = 0.f, a1 = 0.f, a2 = 0.f, a3 = 0.f;
#pragma unroll 4
    for (int d = 0; d < 512; d += 2) {
        float w0 = Wf2[(size_t)d * 256 + j];
        float w1 = Wf2[(size_t)(d + 1) * 256 + j];
        a0 = fmaf(zL[n0 * 512 + d], w0, a0);
        a1 = fmaf(zL[(n0 + 1) * 512 + d], w0, a1);
        a2 = fmaf(zL[n0 * 512 + d + 1], w1, a2);
        a3 = fmaf(zL[(n0 + 1) * 512 + d + 1], w1, a3);
    }
    z2[n0 * 256 + j] = fmaxf(a0 + a2 + bf2[j], 0.f);
    z2[(n0 + 1) * 256 + j] = fmaxf(a1 + a3 + bf2[j], 0.f);
}

// out = z2 @ Wl + bl
__global__ __launch_bounds__(640)
void kout(const float* __restrict__ z2, const float* __restrict__ Wl,
          const float* __restrict__ bl, float* __restrict__ out)
{
    const int t = threadIdx.x;
    const int n = t / NCLS, j = t % NCLS;
    float a = 0.f;
    for (int d = 0; d < 256; ++d)
        a = fmaf(z2[n * 256 + d], Wl[d * NCLS + j], a);
    out[t] = a + bl[j];
}

extern "C" void kernel_launch(void* const* d_in, const int* in_sizes, int n_in,
                              void* d_out, int out_size, void* d_ws, size_t ws_size,
                              hipStream_t stream)
{
    const float* raw  = (const float*)d_in[0];
    const float* fv   = (const float*)d_in[1];
    const int*   vnum = (const int*)d_in[2];
    const float* W1   = (const float*)d_in[3];
    const float* b1   = (const float*)d_in[4];
    const float* W2   = (const float*)d_in[5];
    const float* b2   = (const float*)d_in[6];
    const float* Wf1  = (const float*)d_in[7];
    const float* bf1  = (const float*)d_in[8];
    const float* Wf2  = (const float*)d_in[9];
    const float* bf2  = (const float*)d_in[10];
    const float* Wl   = (const float*)d_in[11];
    const float* bl   = (const float*)d_in[12];
    float* out = (float*)d_out;
    char* ws = (char*)d_ws;
    float* score = (float*)(ws + WS_SCORE);
    float* desc  = (float*)(ws + WS_DESC);
    float* z1    = (float*)(ws + WS_Z1);
    float* z2    = (float*)(ws + WS_Z2);
    float* part  = (float*)(ws + WS_PART);

    k1_mfma<<<2 * NCHUNK, 512, 0, stream>>>(raw, W1, vnum, part);
    k2_score<<<NROWS, 1024, 0, stream>>>(part, b1, W2, b2, score);
    k3_bindesc<<<NB, 512, 0, stream>>>(score, vnum, fv, desc);
    kz1<<<8, 512, 0, stream>>>(desc, Wf1, bf1, z1);
    kz2<<<4, 512, 0, stream>>>(z1, Wf2, bf2, z2);
    kout<<<1, 640, 0, stream>>>(z2, Wl, bl, out);
}

// Round 7
// 229.179 us; speedup vs baseline: 1.3664x; 1.3664x over previous
//
#include <hip/hip_runtime.h>
#include <math.h>

// Problem dims (fixed)
#define NB 16
#define NV 12
#define NROWS 192          // NB*NV
#define DRAW 200704
#define KOUT 256
#define DFEAT 1024
#define NG 8
#define NCLS 40

// K1: 512 blocks = 256 K-chunks x 2 col-halves. KC=784 -> 13 steps of BK=64
// (step 12 has only k<16 valid; invalid slots stage zeros).
#define NCHUNK 256
#define KC 784

// LDS (bytes), single buffer 81920:
// A: 12 tiles x 4096  (tile = 16 rows; 2 k-subs x (1KB hi + 1KB lo))
// B:  8 tiles x 4096  (tile = 16 cols; 2 k-subs x (1KB hi + 1KB lo))
#define ABASE 0
#define BBASE 49152

// workspace layout (bytes)
#define WS_SCORE 0                       // [192] f32
#define WS_PART  4096                    // [192 rows][256 chunks][256 cols] f32

typedef __attribute__((ext_vector_type(8))) short short8;
typedef __attribute__((ext_vector_type(4))) float f32x4;

// split x -> hi(bf16 trunc) + lo(bf16 trunc of exact residual); pack 4 elems
__device__ __forceinline__ void cvt4(float4 v, uint2& hi, uint2& lo) {
    unsigned b0 = __float_as_uint(v.x), b1 = __float_as_uint(v.y);
    unsigned b2 = __float_as_uint(v.z), b3 = __float_as_uint(v.w);
    hi.x = (b0 >> 16) | (b1 & 0xffff0000u);
    hi.y = (b2 >> 16) | (b3 & 0xffff0000u);
    float r0 = v.x - __uint_as_float(b0 & 0xffff0000u);
    float r1 = v.y - __uint_as_float(b1 & 0xffff0000u);
    float r2 = v.z - __uint_as_float(b2 & 0xffff0000u);
    float r3 = v.w - __uint_as_float(b3 & 0xffff0000u);
    lo.x = (__float_as_uint(r0) >> 16) | (__float_as_uint(r1) & 0xffff0000u);
    lo.y = (__float_as_uint(r2) >> 16) | (__float_as_uint(r3) & 0xffff0000u);
}

// issue step-S global loads (coalesced, R4-style) into named reg buffers
#define K1_LOAD(DA, DB, S)                                                     \
  {                                                                            \
    const int koff = (S) * 64;                                                 \
    const float4 f4z = make_float4(0.f, 0.f, 0.f, 0.f);                        \
    _Pragma("unroll") for (int p = 0; p < 6; ++p) {                            \
      bool ok = aact[p] && (akq[p] * 4 + koff < KC);                           \
      DA[p] = ok ? *(const float4*)(aptr[p] + koff) : f4z;                     \
    }                                                                          \
    _Pragma("unroll") for (int q = 0; q < 16; ++q) {                           \
      int dd = bkh * 16 + q + koff;                                            \
      DB[q] = (dd < KC) ? bptr[(size_t)(koff + q) * KOUT] : 0.f;               \
    }                                                                          \
  }

// cvt regs -> LDS (single buffer)
#define K1_WRITE(CA, CB)                                                       \
  {                                                                            \
    _Pragma("unroll") for (int p = 0; p < 6; ++p) {                            \
      uint2 hi, lo; cvt4(CA[p], hi, lo);                                       \
      *(uint2*)(smem + awoff[p]) = hi;                                         \
      *(uint2*)(smem + awoff[p] + 1024) = lo;                                  \
    }                                                                          \
    _Pragma("unroll") for (int qh = 0; qh < 2; ++qh) {                         \
      uint2 ha, la, hb, lb;                                                    \
      cvt4(make_float4(CB[qh*8+0], CB[qh*8+1], CB[qh*8+2], CB[qh*8+3]), ha, la); \
      cvt4(make_float4(CB[qh*8+4], CB[qh*8+5], CB[qh*8+6], CB[qh*8+7]), hb, lb); \
      uint4 hv; hv.x = ha.x; hv.y = ha.y; hv.z = hb.x; hv.w = hb.y;            \
      uint4 lv; lv.x = la.x; lv.y = la.y; lv.z = lb.x; lv.w = lb.y;            \
      *(uint4*)(smem + bwoff[qh]) = hv;                                        \
      *(uint4*)(smem + bwoff[qh] + 1024) = lv;                                 \
    }                                                                          \
  }

// fragment reads + 72 MFMAs (2 k-subs x 3x4 frags x bf16x3)
#define K1_MMA()                                                               \
  {                                                                            \
    _Pragma("unroll") for (int kf = 0; kf < 2; ++kf) {                         \
      short8 ah[3], al[3];                                                     \
      _Pragma("unroll") for (int tm = 0; tm < 3; ++tm) {                       \
        int off = ABASE + (wm * 3 + tm) * 4096 + kf * 2048 + aroff;            \
        ah[tm] = *(const short8*)(smem + off);                                 \
        al[tm] = *(const short8*)(smem + off + 1024);                          \
      }                                                                        \
      _Pragma("unroll") for (int tn = 0; tn < 4; ++tn) {                       \
        int off = BBASE + (wn * 4 + tn) * 4096 + kf * 2048 +                   \
                  ((lane << 4) ^ ((tn & 1) << 6));                             \
        short8 bh = *(const short8*)(smem + off);                              \
        short8 bl = *(const short8*)(smem + off + 1024);                       \
        _Pragma("unroll") for (int tm = 0; tm < 3; ++tm) {                     \
          acc[tm][tn] = __builtin_amdgcn_mfma_f32_16x16x32_bf16(ah[tm], bh, acc[tm][tn], 0, 0, 0); \
          acc[tm][tn] = __builtin_amdgcn_mfma_f32_16x16x32_bf16(ah[tm], bl, acc[tm][tn], 0, 0, 0); \
          acc[tm][tn] = __builtin_amdgcn_mfma_f32_16x16x32_bf16(al[tm], bh, acc[tm][tn], 0, 0, 0); \
        }                                                                      \
      }                                                                        \
    }                                                                          \
  }

// one K-step (single buffer, 2 barriers, R4 discipline): raw top barrier
// (prev reads complete before it -- each wave's MFMAs already consumed them),
// issue next loads (stay in flight), cvt+write cur, lgkm+barrier, MMA.
#define K1_STEP(CA, CB, NA, NB_, S, DOLOAD)                                    \
  {                                                                            \
    __builtin_amdgcn_sched_barrier(0);                                         \
    __builtin_amdgcn_s_barrier();                                              \
    __builtin_amdgcn_sched_barrier(0);                                         \
    if (DOLOAD) K1_LOAD(NA, NB_, (S) + 1);                                     \
    K1_WRITE(CA, CB);                                                          \
    asm volatile("s_waitcnt lgkmcnt(0)" ::: "memory");                         \
    __builtin_amdgcn_s_barrier();                                              \
    __builtin_amdgcn_sched_barrier(0);                                         \
    K1_MMA();                                                                  \
  }

// MFMA split-K/split-N GEMM, BK=64. Co-XCD bid map keeps a chunk's two
// col-halves on one XCD (A reuse L2-hits). 8 waves 4(M)x2(N); wave owns
// 48 rows x 64 cols = 3x4 fragments. bf16x3: acc += ah*bh + ah*bl + al*bh.
__global__ __launch_bounds__(512, 2)
void k1_mfma(const float* __restrict__ raw, const float* __restrict__ W1,
             const int* __restrict__ vnum, float* __restrict__ part)
{
    __shared__ __align__(16) char smem[81920];
    const int t = threadIdx.x;
    const int g8 = blockIdx.x & 7;
    const int i8 = blockIdx.x >> 3;
    const int c = g8 * 32 + (i8 >> 1);
    const int colbase = (i8 & 1) * 128;
    const int d0 = c * KC;

    // ---- A staging: 6 passes, idx=p*512+t: row=idx>>4, kq=idx&15 (4 k each)
    int akq[6];
    bool aact[6];
    const float* aptr[6];
    int awoff[6];
#pragma unroll
    for (int p = 0; p < 6; ++p) {
        int idx = p * 512 + t;
        int row = idx >> 4, kq = idx & 15;
        akq[p] = kq;
        aact[p] = (row % NV) < vnum[row / NV];
        aptr[p] = raw + (size_t)row * DRAW + d0 + kq * 4;
        int kq7 = kq & 7, sub = kq >> 3;
        int off = ABASE + (row >> 4) * 4096 + sub * 2048
                + (((row & 15) + ((kq7 >> 1) << 4)) << 4) + ((kq7 & 1) << 3);
        off ^= ((kq7 >> 1) & 1) << 6;
        awoff[p] = off;
    }
    // ---- B staging: col = t&127, bkh = t>>7 (16 k each, sub = bkh>>1) ----
    const int bcol = t & 127;
    const int bkh = t >> 7;
    const float* bptr = W1 + (size_t)(d0 + bkh * 16) * KOUT + colbase + bcol;
    const int bTN = bcol >> 4;
    int bwoff[2];
#pragma unroll
    for (int qh = 0; qh < 2; ++qh) {
        int oct = (bkh & 1) * 2 + qh;
        int off = BBASE + bTN * 4096 + (bkh >> 1) * 2048
                + (((bcol & 15) + (oct << 4)) << 4);
        off ^= (bTN & 1) << 6;
        bwoff[qh] = off;
    }

    // wave/fragment geometry
    const int lane = t & 63;
    const int wave = t >> 6;
    const int wm = wave >> 1, wn = wave & 1;
    const int aroff = (lane << 4) ^ (((lane >> 4) & 1) << 6);

    f32x4 acc[3][4];
#pragma unroll
    for (int i = 0; i < 3; ++i)
#pragma unroll
        for (int j = 0; j < 4; ++j) acc[i][j] = (f32x4){0.f, 0.f, 0.f, 0.f};

    float4 Aa[6], Ab[6];
    float Ba[16], Bb[16];
    K1_LOAD(Aa, Ba, 0);

    // 13 steps: 0..11 load-ahead, 12 MMA-only
#pragma unroll 1
    for (int sp = 0; sp < 6; ++sp) {
        K1_STEP(Aa, Ba, Ab, Bb, 2 * sp, 1);
        K1_STEP(Ab, Bb, Aa, Ba, 2 * sp + 1, 1);
    }
    K1_STEP(Aa, Ba, Ab, Bb, 12, 0);

    // ---- epilogue: part[row][chunk][col]; C/D: col=lane&15, row=(lane>>4)*4+r
#pragma unroll
    for (int tm = 0; tm < 3; ++tm) {
        int row0 = wm * 48 + tm * 16 + ((lane >> 4) << 2);
#pragma unroll
        for (int tn = 0; tn < 4; ++tn) {
            int col = colbase + wn * 64 + tn * 16 + (lane & 15);
            f32x4 a = acc[tm][tn];
#pragma unroll
            for (int r = 0; r < 4; ++r)
                part[((size_t)(row0 + r) * NCHUNK + c) * KOUT + col] = a[r];
        }
    }
}

// fused 256-chunk reduce + score head. One block per row; part[row] is a
// CONTIGUOUS 256KB stream (new layout) -> coalesced, prefetch-friendly.
__global__ __launch_bounds__(1024)
void k2_score(const float* __restrict__ part, const float* __restrict__ b1,
              const float* __restrict__ W2, const float* __restrict__ b2,
              float* __restrict__ score)
{
    const int row = blockIdx.x, t = threadIdx.x;
    const int col = t & 255, cg = t >> 8;
    __shared__ float red[4][KOUT];
    __shared__ float r2[4];
    const float* p = part + ((size_t)row * NCHUNK + cg * 64) * KOUT + col;
    float s = 0.f;
#pragma unroll 8
    for (int i = 0; i < 64; ++i) s += p[(size_t)i * KOUT];
    red[cg][col] = s;
    __syncthreads();
    if (t < 256) {
        float v = red[0][col] + red[1][col] + red[2][col] + red[3][col];
        float h = fmaxf(v + b1[col], 0.f) * W2[col];
        for (int o = 32; o > 0; o >>= 1) h += __shfl_down(h, o, 64);
        if ((t & 63) == 0) r2[t >> 6] = h;
    }
    __syncthreads();
    if (t == 0) {
        float sm = r2[0] + r2[1] + r2[2] + r2[3];
        float sraw = fmaxf(sm + b2[0], 0.f);
        score[row] = 1.f / (1.f + expf(-tanhf(fabsf(sraw))));
    }
}

// fused tail: binning->coeff->desc->3-layer classifier. One block per sample.
// (verified in R4 bench)
__global__ __launch_bounds__(512)
void k5f(const float* __restrict__ score, const int* __restrict__ vnum,
         const float* __restrict__ fv,
         const float* __restrict__ Wf1, const float* __restrict__ bf1,
         const float* __restrict__ Wf2, const float* __restrict__ bf2,
         const float* __restrict__ Wl,  const float* __restrict__ bl,
         float* __restrict__ out)
{
    const int n = blockIdx.x, t = threadIdx.x;
    __shared__ float coeffL[NV], descL[DFEAT], z1L[512], z2L[256];
    __shared__ float wsum[NG], wt[NG], outred[8][NCLS];
    __shared__ int cnt[NG];
    __shared__ float wtotS;
    if (t < NG) { cnt[t] = 0; wsum[t] = 0.f; }
    __syncthreads();
    const int vn = vnum[n];
    const bool act = (t < NV) && (t < vn);
    float sc = 0.f; int b = 0;
    if (act) {
        sc = score[n * NV + t];
        b = (int)floorf(sc * 8.f); b = b < 0 ? 0 : (b > 7 ? 7 : b);
        atomicAdd(&cnt[b], 1);
    }
    __syncthreads();
    if (act) atomicAdd(&wsum[b], ceilf(sc * (float)cnt[b]));
    __syncthreads();
    if (t < NG) wt[t] = (cnt[t] > 0) ? wsum[t] / (float)cnt[t] : 0.f;
    __syncthreads();
    if (t == 0) { float x = 0.f; for (int g = 0; g < NG; ++g) x += wt[g]; wtotS = x; }
    __syncthreads();
    if (t < NV) coeffL[t] = act ? wt[b] / ((float)cnt[b] * wtotS) : 0.f;
    __syncthreads();
#pragma unroll
    for (int p = 0; p < 2; ++p) {
        int d = t + p * 512;
        float a = 0.f;
#pragma unroll
        for (int v = 0; v < NV; ++v)
            a = fmaf(coeffL[v], fv[((size_t)n * NV + v) * DFEAT + d], a);
        descL[d] = a;
    }
    __syncthreads();
    {
        float a = 0.f;
#pragma unroll 8
        for (int d = 0; d < DFEAT; ++d)
            a = fmaf(descL[d], Wf1[(size_t)d * 512 + t], a);
        z1L[t] = fmaxf(a + bf1[t], 0.f);
    }
    __syncthreads();
    if (t < 256) {
        float a = 0.f;
#pragma unroll 8
        for (int d = 0; d < 512; ++d)
            a = fmaf(z1L[d], Wf2[(size_t)d * 256 + t], a);
        z2L[t] = fmaxf(a + bf2[t], 0.f);
    }
    __syncthreads();
    if (t < 320) {
        int j = t % NCLS, seg = t / NCLS;
        float a = 0.f;
#pragma unroll
        for (int dd = 0; dd < 32; ++dd) {
            int d = seg * 32 + dd;
            a = fmaf(z2L[d], Wl[d * NCLS + j], a);
        }
        outred[seg][j] = a;
    }
    __syncthreads();
    if (t < NCLS) {
        float a = bl[t];
#pragma unroll
        for (int s8 = 0; s8 < 8; ++s8) a += outred[s8][t];
        out[n * NCLS + t] = a;
    }
}

extern "C" void kernel_launch(void* const* d_in, const int* in_sizes, int n_in,
                              void* d_out, int out_size, void* d_ws, size_t ws_size,
                              hipStream_t stream)
{
    const float* raw  = (const float*)d_in[0];
    const float* fv   = (const float*)d_in[1];
    const int*   vnum = (const int*)d_in[2];
    const float* W1   = (const float*)d_in[3];
    const float* b1   = (const float*)d_in[4];
    const float* W2   = (const float*)d_in[5];
    const float* b2   = (const float*)d_in[6];
    const float* Wf1  = (const float*)d_in[7];
    const float* bf1  = (const float*)d_in[8];
    const float* Wf2  = (const float*)d_in[9];
    const float* bf2  = (const float*)d_in[10];
    const float* Wl   = (const float*)d_in[11];
    const float* bl   = (const float*)d_in[12];
    float* out = (float*)d_out;
    char* ws = (char*)d_ws;
    float* score = (float*)(ws + WS_SCORE);
    float* part  = (float*)(ws + WS_PART);

    k1_mfma<<<2 * NCHUNK, 512, 0, stream>>>(raw, W1, vnum, part);
    k2_score<<<NROWS, 1024, 0, stream>>>(part, b1, W2, b2, score);
    k5f<<<NB, 512, 0, stream>>>(score, vnum, fv, Wf1, bf1, Wf2, bf2, Wl, bl, out);
}